// Round 9
// baseline (234.650 us; speedup 1.0000x reference)
//
#include <hip/hip_runtime.h>
#include <math.h>

#define KDIM 4096
#define SPLITS 8
#define WAYS 32
#define MAXPB 256
#define NQKV 4608
#define NDENSE 4096

typedef __attribute__((ext_vector_type(8))) short bh8;
typedef __attribute__((ext_vector_type(4))) float f32x4;

__device__ __forceinline__ short f2bf(float x) {
    union { float f; unsigned u; } v; v.f = x;
    unsigned r = v.u + 0x7FFFu + ((v.u >> 16) & 1u);   // RNE
    return (short)(r >> 16);
}
__device__ __forceinline__ float bf2f(short h) {
    union { unsigned u; float f; } v;
    v.u = ((unsigned)(unsigned short)h) << 16;
    return v.f;
}

// Split x[64][4096] f32 -> hi,lo bf16 (hi = RNE(x), lo = RNE(x - hi)).
__global__ __launch_bounds__(256) void prep_hilo(
    const float* __restrict__ x, unsigned short* __restrict__ hi,
    unsigned short* __restrict__ lo)
{
    const int i = (blockIdx.x * 256 + threadIdx.x) * 4;
    float4 v = *(const float4*)&x[i];
    unsigned short h4[4], l4[4];
    float vf[4] = {v.x, v.y, v.z, v.w};
    #pragma unroll
    for (int j = 0; j < 4; ++j) {
        short hh = f2bf(vf[j]);
        h4[j] = (unsigned short)hh;
        l4[j] = (unsigned short)f2bf(vf[j] - bf2f(hh));
    }
    *(ushort4*)&hi[i] = make_ushort4(h4[0], h4[1], h4[2], h4[3]);
    *(ushort4*)&lo[i] = make_ushort4(l4[0], l4[1], l4[2], l4[3]);
}

// Fused MFMA GEMM, intra-block split-K: block = 16 cols, 4 waves x K=1024,
// LDS merge, fused epilogue. MODE 0: QKV + RoPE -> q_rope/knew/vnew.
// MODE 1: dense -> out. acc += ah*wh + al*wh + ah*wl.
template<int MODE>
__global__ __launch_bounds__(256) void gemm_fused(
    const unsigned short* __restrict__ A_hi, const unsigned short* __restrict__ A_lo,
    const float* __restrict__ W, const int* __restrict__ lens,
    float* __restrict__ oq, float* __restrict__ ok, float* __restrict__ ov)
{
    __shared__ float sM[3][64][16];      // 12 KB merge buffer
    const int tid = threadIdx.x;
    const int wv = tid >> 6;
    const int l = tid & 63;
    const int lr = l & 15;
    const int h = l >> 4;
    const int n0 = blockIdx.x * 16;
    const int kbase = wv * 1024;

    const float* wrow = &W[(size_t)(n0 + lr) * KDIM + h * 8];
    const unsigned short* pah[4];
    const unsigned short* pal[4];
    #pragma unroll
    for (int mt = 0; mt < 4; ++mt) {
        pah[mt] = &A_hi[(mt * 16 + lr) * KDIM + h * 8];
        pal[mt] = &A_lo[(mt * 16 + lr) * KDIM + h * 8];
    }

    f32x4 acc[4];
    #pragma unroll
    for (int mt = 0; mt < 4; ++mt) acc[mt] = (f32x4){0.f, 0.f, 0.f, 0.f};

    // W prefetch 2 kt deep (named regs), A prefetch 1 kt deep.
    float4 wa0, wb0, wa1, wb1;
    bh8 ahc[4], alc[4], ahn[4], aln[4];
    wa0 = *(const float4*)&wrow[kbase];
    wb0 = *(const float4*)&wrow[kbase + 4];
    wa1 = *(const float4*)&wrow[kbase + 32];
    wb1 = *(const float4*)&wrow[kbase + 36];
    #pragma unroll
    for (int mt = 0; mt < 4; ++mt) {
        ahc[mt] = *(const bh8*)&pah[mt][kbase];
        alc[mt] = *(const bh8*)&pal[mt][kbase];
    }

    auto body = [&](float4& pwa, float4& pwb, int kcur) {
        float4 cw0 = pwa, cw1 = pwb;
        if (kcur + 64 < 1024) {
            pwa = *(const float4*)&wrow[kbase + kcur + 64];
            pwb = *(const float4*)&wrow[kbase + kcur + 68];
        }
        if (kcur + 32 < 1024) {
            #pragma unroll
            for (int mt = 0; mt < 4; ++mt) {
                ahn[mt] = *(const bh8*)&pah[mt][kbase + kcur + 32];
                aln[mt] = *(const bh8*)&pal[mt][kbase + kcur + 32];
            }
        }
        bh8 whi, wlo;
        float wf[8] = {cw0.x, cw0.y, cw0.z, cw0.w, cw1.x, cw1.y, cw1.z, cw1.w};
        #pragma unroll
        for (int e = 0; e < 8; ++e) {
            short hh = f2bf(wf[e]);
            whi[e] = hh;
            wlo[e] = f2bf(wf[e] - bf2f(hh));
        }
        #pragma unroll
        for (int mt = 0; mt < 4; ++mt) {
            acc[mt] = __builtin_amdgcn_mfma_f32_16x16x32_bf16(ahc[mt], whi, acc[mt], 0, 0, 0);
            acc[mt] = __builtin_amdgcn_mfma_f32_16x16x32_bf16(alc[mt], whi, acc[mt], 0, 0, 0);
            acc[mt] = __builtin_amdgcn_mfma_f32_16x16x32_bf16(ahc[mt], wlo, acc[mt], 0, 0, 0);
        }
        if (kcur + 32 < 1024) {
            #pragma unroll
            for (int mt = 0; mt < 4; ++mt) { ahc[mt] = ahn[mt]; alc[mt] = aln[mt]; }
        }
    };

    for (int kt2 = 0; kt2 < 16; ++kt2) {
        body(wa0, wb0, kt2 * 64);
        body(wa1, wb1, kt2 * 64 + 32);
    }

    // intra-block K-merge via LDS
    if (wv > 0) {
        #pragma unroll
        for (int mt = 0; mt < 4; ++mt)
            #pragma unroll
            for (int j = 0; j < 4; ++j)
                sM[wv - 1][mt * 16 + h * 4 + j][lr] = acc[mt][j];
    }
    __syncthreads();
    if (wv == 0) {
        const int n = n0 + lr;
        #pragma unroll
        for (int mt = 0; mt < 4; ++mt) {
            #pragma unroll
            for (int j = 0; j < 4; ++j) {
                const int m = mt * 16 + h * 4 + j;
                float x = acc[mt][j] + sM[0][m][lr] + sM[1][m][lr] + sM[2][m][lr];
                if (MODE == 1) {
                    oq[(size_t)m * 4096 + n] = x;
                } else {
                    // block-uniform region: all-Q (n<4096), all-K, or all-V
                    if (n < 4352) {
                        const int d = n & 127;
                        float xo = __shfl_xor(x, 1);   // partner col (same m)
                        float xr = x;
                        if (d < 64) {
                            const int pos = lens[m] - 1;
                            double inv = pow(10000.0, -(double)(d >> 1) / 32.0);
                            double ang = (double)pos * inv;
                            float cc = (float)cos(ang), ss = (float)sin(ang);
                            xr = ((d & 1) == 0) ? (x * cc - xo * ss)
                                                : (x * cc + xo * ss);
                        }
                        if (n < 4096) {
                            oq[(size_t)m * 4096 + n] = xr;
                        } else {
                            const int kk = n - 4096;
                            ok[(m * 2 + (kk >> 7)) * 128 + (kk & 127)] = xr;
                        }
                    } else {
                        const int vv2 = n - 4352;
                        ov[(m * 2 + (vv2 >> 7)) * 128 + (vv2 & 127)] = x;
                    }
                }
            }
        }
    }
}

// MFMA flash-decode (round-5 known-best, verbatim).
__global__ __launch_bounds__(256) void attn_mfma(
    const float* __restrict__ qr, const float* __restrict__ knew,
    const float* __restrict__ vnew, const float* __restrict__ kcache,
    const float* __restrict__ vcache, const int* __restrict__ bt,
    const int* __restrict__ lens, float* __restrict__ pO, float* __restrict__ pML)
{
    const int split = blockIdx.x;
    const int kh = blockIdx.y;
    const int b = blockIdx.z;
    const int tid = threadIdx.x;
    const int wv = tid >> 6;
    const int l = tid & 63;
    const int g = l & 15;
    const int h = l >> 4;
    const int way = split * 4 + wv;

    __shared__ unsigned int sP[4][256];
    __shared__ float sO[3][16][132];
    __shared__ float sML[3][2][16];

    const int len = lens[b];
    const int nchunks = (len + 31) >> 5;
    const size_t nbase = ((size_t)(b * 2 + kh)) * 128;

    const float scale = 0.08838834764831845f;
    bh8 qf[4];
    {
        const float* qrow = &qr[((size_t)(b * 32 + kh * 16 + g)) * 128 + h * 8];
        #pragma unroll
        for (int dc = 0; dc < 4; ++dc) {
            float4 a = *(const float4*)&qrow[dc * 32];
            float4 c = *(const float4*)&qrow[dc * 32 + 4];
            qf[dc][0] = f2bf(a.x * scale); qf[dc][1] = f2bf(a.y * scale);
            qf[dc][2] = f2bf(a.z * scale); qf[dc][3] = f2bf(a.w * scale);
            qf[dc][4] = f2bf(c.x * scale); qf[dc][5] = f2bf(c.y * scale);
            qf[dc][6] = f2bf(c.z * scale); qf[dc][7] = f2bf(c.w * scale);
        }
    }

    float m = -INFINITY, lacc = 0.f;
    f32x4 oacc[8];
    #pragma unroll
    for (int dt = 0; dt < 8; ++dt) oacc[dt] = (f32x4){0.f, 0.f, 0.f, 0.f};

    for (int c = way; c < nchunks; c += WAYS) {
        const int s0 = c * 32;
        const int blk0 = bt[b * MAXPB + 2 * c];
        const int blk1 = bt[b * MAXPB + 2 * c + 1];

        const float* rowK0 = (s0 + g == len - 1) ? &knew[nbase]
            : &kcache[(((size_t)blk0 * 16 + g) * 2 + kh) * 128];
        const float* rowK1 = (s0 + 16 + g == len - 1) ? &knew[nbase]
            : &kcache[(((size_t)blk1 * 16 + g) * 2 + kh) * 128];
        float4 k0[8], k1[8];
        #pragma unroll
        for (int dc = 0; dc < 4; ++dc) {
            k0[2*dc]   = *(const float4*)&rowK0[dc * 32 + h * 8];
            k0[2*dc+1] = *(const float4*)&rowK0[dc * 32 + h * 8 + 4];
            k1[2*dc]   = *(const float4*)&rowK1[dc * 32 + h * 8];
            k1[2*dc+1] = *(const float4*)&rowK1[dc * 32 + h * 8 + 4];
        }

        float vv[8][8];
        #pragma unroll
        for (int e = 0; e < 8; ++e) {
            const int p = h * 8 + e;
            const int s = s0 + p;
            const float* rowV = (s == len - 1) ? &vnew[nbase]
                : &vcache[(((size_t)(p < 16 ? blk0 : blk1) * 16 + (p & 15)) * 2 + kh) * 128];
            #pragma unroll
            for (int dt = 0; dt < 8; ++dt)
                vv[e][dt] = rowV[dt * 16 + g];
        }

        f32x4 sa0 = (f32x4){0.f,0.f,0.f,0.f};
        f32x4 sa1 = (f32x4){0.f,0.f,0.f,0.f};
        #pragma unroll
        for (int dc = 0; dc < 4; ++dc) {
            bh8 a0, a1;
            a0[0]=f2bf(k0[2*dc].x);   a0[1]=f2bf(k0[2*dc].y);
            a0[2]=f2bf(k0[2*dc].z);   a0[3]=f2bf(k0[2*dc].w);
            a0[4]=f2bf(k0[2*dc+1].x); a0[5]=f2bf(k0[2*dc+1].y);
            a0[6]=f2bf(k0[2*dc+1].z); a0[7]=f2bf(k0[2*dc+1].w);
            a1[0]=f2bf(k1[2*dc].x);   a1[1]=f2bf(k1[2*dc].y);
            a1[2]=f2bf(k1[2*dc].z);   a1[3]=f2bf(k1[2*dc].w);
            a1[4]=f2bf(k1[2*dc+1].x); a1[5]=f2bf(k1[2*dc+1].y);
            a1[6]=f2bf(k1[2*dc+1].z); a1[7]=f2bf(k1[2*dc+1].w);
            sa0 = __builtin_amdgcn_mfma_f32_16x16x32_bf16(a0, qf[dc], sa0, 0, 0, 0);
            sa1 = __builtin_amdgcn_mfma_f32_16x16x32_bf16(a1, qf[dc], sa1, 0, 0, 0);
        }

        float sc[8];
        #pragma unroll
        for (int j = 0; j < 4; ++j) {
            sc[j]     = (s0 + 4*h + j      < len) ? sa0[j] : -INFINITY;
            sc[4 + j] = (s0 + 16 + 4*h + j < len) ? sa1[j] : -INFINITY;
        }
        float tmax = sc[0];
        #pragma unroll
        for (int j = 1; j < 8; ++j) tmax = fmaxf(tmax, sc[j]);
        tmax = fmaxf(tmax, __shfl_xor(tmax, 16));
        tmax = fmaxf(tmax, __shfl_xor(tmax, 32));
        const float m_new = fmaxf(m, tmax);
        const float corr = expf(m - m_new);
        float pe[8], ls = 0.f;
        #pragma unroll
        for (int j = 0; j < 8; ++j) { pe[j] = expf(sc[j] - m_new); ls += pe[j]; }
        ls += __shfl_xor(ls, 16);
        ls += __shfl_xor(ls, 32);
        lacc = lacc * corr + ls;
        m = m_new;
        #pragma unroll
        for (int dt = 0; dt < 8; ++dt) {
            oacc[dt][0] *= corr; oacc[dt][1] *= corr;
            oacc[dt][2] *= corr; oacc[dt][3] *= corr;
        }

        unsigned int* myP = sP[wv];
        #pragma unroll
        for (int ph = 0; ph < 2; ++ph)
            #pragma unroll
            for (int t2 = 0; t2 < 2; ++t2) {
                unsigned lo = (unsigned short)f2bf(pe[ph*4 + 2*t2]);
                unsigned hi = (unsigned short)f2bf(pe[ph*4 + 2*t2 + 1]);
                myP[g * 16 + ph * 8 + 2 * h + t2] = lo | (hi << 16);
            }
        asm volatile("s_waitcnt lgkmcnt(0)" ::: "memory");
        bh8 pf = *(const bh8*)&myP[g * 16 + 4 * h];

        #pragma unroll
        for (int dt = 0; dt < 8; ++dt) {
            bh8 av;
            #pragma unroll
            for (int e = 0; e < 8; ++e) av[e] = f2bf(vv[e][dt]);
            oacc[dt] = __builtin_amdgcn_mfma_f32_16x16x32_bf16(av, pf, oacc[dt], 0, 0, 0);
        }
    }

    if (wv > 0) {
        #pragma unroll
        for (int dt = 0; dt < 8; ++dt)
            #pragma unroll
            for (int j = 0; j < 4; ++j)
                sO[wv-1][g][dt*16 + 4*h + j] = oacc[dt][j];
        if (l < 16) {
            sML[wv-1][0][g] = m;
            sML[wv-1][1][g] = lacc;
        }
    }
    __syncthreads();
    if (wv == 0) {
        float M = m;
        #pragma unroll
        for (int i = 0; i < 3; ++i) M = fmaxf(M, sML[i][0][g]);
        const float w0 = expf(m - M);
        float L = lacc * w0;
        float wi[3];
        #pragma unroll
        for (int i = 0; i < 3; ++i) {
            wi[i] = expf(sML[i][0][g] - M);
            L += sML[i][1][g] * wi[i];
        }
        size_t base = ((((size_t)(b * 2 + kh)) * SPLITS + split) * 16 + g) * 128;
        #pragma unroll
        for (int dt = 0; dt < 8; ++dt)
            #pragma unroll
            for (int j = 0; j < 4; ++j) {
                float o = oacc[dt][j] * w0;
                #pragma unroll
                for (int i = 0; i < 3; ++i)
                    o += sO[i][g][dt*16 + 4*h + j] * wi[i];
                pO[base + dt*16 + 4*h + j] = o;
            }
        if (l < 16) {
            size_t mb = ((((size_t)(b * 2 + kh)) * SPLITS + split) * 16 + g) * 2;
            pML[mb] = M;
            pML[mb + 1] = L;
        }
    }
}

// Combine splits AND emit dense-GEMM input pre-split to bf16 hi/lo.
__global__ __launch_bounds__(256) void attn_combine(
    const float* __restrict__ pO, const float* __restrict__ pML,
    unsigned short* __restrict__ a_hi, unsigned short* __restrict__ a_lo)
{
    const int bk = blockIdx.x;
    const int tid = threadIdx.x;
    const int g = tid >> 4;
    const int dh = tid & 15;

    float ms[SPLITS], ls[SPLITS];
    float M = -INFINITY;
    #pragma unroll
    for (int s = 0; s < SPLITS; ++s) {
        size_t mb = (((size_t)bk * SPLITS + s) * 16 + g) * 2;
        ms[s] = pML[mb]; ls[s] = pML[mb + 1];
        M = fmaxf(M, ms[s]);
    }
    float L = 0.f;
    #pragma unroll
    for (int s = 0; s < SPLITS; ++s) L += ls[s] * expf(ms[s] - M);

    float acc[8] = {0, 0, 0, 0, 0, 0, 0, 0};
    #pragma unroll
    for (int s = 0; s < SPLITS; ++s) {
        float wgt = expf(ms[s] - M);
        const float* src = &pO[(((size_t)bk * SPLITS + s) * 16 + g) * 128 + dh * 8];
        #pragma unroll
        for (int r = 0; r < 8; ++r) acc[r] += wgt * src[r];
    }
    const float invL = 1.f / L;
    const int b = bk >> 1, kh = bk & 1;
    const size_t idx = (size_t)b * 4096 + (kh * 16 + g) * 128 + dh * 8;
    unsigned short hbuf[8], lbuf[8];
    #pragma unroll
    for (int r = 0; r < 8; ++r) {
        float o = acc[r] * invL;
        short hh = f2bf(o);
        hbuf[r] = (unsigned short)hh;
        lbuf[r] = (unsigned short)f2bf(o - bf2f(hh));
    }
    *(int4*)&a_hi[idx] = *(int4*)hbuf;
    *(int4*)&a_lo[idx] = *(int4*)lbuf;
}

extern "C" void kernel_launch(void* const* d_in, const int* in_sizes, int n_in,
                              void* d_out, int out_size, void* d_ws, size_t ws_size,
                              hipStream_t stream) {
    const float* hidden = (const float*)d_in[0];
    const float* wqkv   = (const float*)d_in[1];
    const float* wdense = (const float*)d_in[2];
    const float* kcache = (const float*)d_in[3];
    const float* vcache = (const float*)d_in[4];
    const int*   bt     = (const int*)d_in[5];
    const int*   lens   = (const int*)d_in[7];
    float* out = (float*)d_out;

    float* ws     = (float*)d_ws;
    float* q_rope = ws;                       // 262144 f
    float* k_new  = ws + 262144;              // 16384 f
    float* v_new  = ws + 278528;              // 16384 f
    unsigned short* A_hi = (unsigned short*)(ws + 294912);   // 262144 us
    unsigned short* A_lo = A_hi + 262144;                    // 262144 us
    float* pO     = ws + 557056;              // 2097152 f
    float* pML    = ws + 2654208;             // 32768 f
    // total ws use: 2686976 floats = 10.7 MB

    prep_hilo<<<dim3(256), dim3(256), 0, stream>>>(hidden, A_hi, A_lo);
    gemm_fused<0><<<dim3(NQKV / 16), dim3(256), 0, stream>>>(
        A_hi, A_lo, wqkv, lens, q_rope, k_new, v_new);
    attn_mfma<<<dim3(SPLITS, 2, 64), dim3(256), 0, stream>>>(
        q_rope, k_new, v_new, kcache, vcache, bt, lens, pO, pML);
    attn_combine<<<dim3(128), dim3(256), 0, stream>>>(pO, pML, A_hi, A_lo);
    gemm_fused<1><<<dim3(NDENSE / 16), dim3(256), 0, stream>>>(
        A_hi, A_lo, wdense, nullptr, out, nullptr, nullptr);
}